// Round 4
// baseline (192.303 us; speedup 1.0000x reference)
//
#include <hip/hip_runtime.h>
#include <hip/hip_bf16.h>
#include <math.h>

#define FEAT 256
#define NNODES 262144
#define NGRAPHS 8192
#define RUN 16  // contiguous nodes per 16-lane group

typedef short bf16x8 __attribute__((ext_vector_type(8)));
typedef unsigned short u16x8 __attribute__((ext_vector_type(8)));
typedef float f32x4 __attribute__((ext_vector_type(4)));

__device__ __forceinline__ unsigned short f2bf(float f) {
    unsigned u = __float_as_uint(f);
    u += 0x7fffu + ((u >> 16) & 1u);
    return (unsigned short)(u >> 16);
}

__device__ __forceinline__ float waveReduceSum(float v) {
#pragma unroll
    for (int m = 32; m > 0; m >>= 1) v += __shfl_xor(v, m, 64);
    return v;
}

__device__ __forceinline__ float sigmoidf(float x) { return 1.f / (1.f + expf(-x)); }

// ---------------- fused prep: gz | W_ih->bf16 | W_hh->bf16 | W_proj^T->bf16 |
//                  zero unnorm accumulator | zero sden
__global__ __launch_bounds__(256) void k_prep(
    const float* __restrict__ g_feats, const float* __restrict__ W_log,
    const float* __restrict__ b_log, const float* __restrict__ W_ih,
    const float* __restrict__ W_hh, const float* __restrict__ W_proj,
    float* __restrict__ gz, unsigned short* __restrict__ wihb,
    unsigned short* __restrict__ whhb, unsigned short* __restrict__ wptb,
    float* __restrict__ unorm, float* __restrict__ sden) {
    const int blk = blockIdx.x;
    const int tid = threadIdx.x;
    if (blk < 2048) {
        // gz[b] = dot(relu(g_feats[b]), W_log[0:F]) + b_log; 4 graphs/block
        int gw = blk * 4 + (tid >> 6);
        int lane = tid & 63;
        float4 gf = *(const float4*)(g_feats + (size_t)gw * FEAT + lane * 4);
        float4 wl = *(const float4*)(W_log + lane * 4);
        float d = fmaxf(gf.x, 0.f) * wl.x + fmaxf(gf.y, 0.f) * wl.y +
                  fmaxf(gf.z, 0.f) * wl.z + fmaxf(gf.w, 0.f) * wl.w;
        d = waveReduceSum(d);
        if (lane == 0) gz[gw] = d + b_log[0];
    } else if (blk < 2240) {  // W_ih -> bf16
        int i = (blk - 2048) * 1024 + tid * 4;
        float4 v = *(const float4*)(W_ih + i);
        ushort4 o;
        o.x = f2bf(v.x); o.y = f2bf(v.y); o.z = f2bf(v.z); o.w = f2bf(v.w);
        *(ushort4*)(wihb + i) = o;
    } else if (blk < 2432) {  // W_hh -> bf16
        int i = (blk - 2240) * 1024 + tid * 4;
        float4 v = *(const float4*)(W_hh + i);
        ushort4 o;
        o.x = f2bf(v.x); o.y = f2bf(v.y); o.z = f2bf(v.z); o.w = f2bf(v.w);
        *(ushort4*)(whhb + i) = o;
    } else if (blk < 2688) {  // Wt[f][k] = W_proj[k][f]
        int f = blk - 2432;
        wptb[f * 256 + tid] = f2bf(W_proj[tid * 256 + f]);
    } else if (blk < 4736) {  // zero unnorm (8 MB)
        int i = (blk - 2688) * 1024 + tid * 4;
        *(float4*)(unorm + i) = (float4){0.f, 0.f, 0.f, 0.f};
    } else {  // zero sden (32 KB)
        int i = (blk - 4736) * 1024 + tid * 4;
        *(float4*)(sden + i) = (float4){0.f, 0.f, 0.f, 0.f};
    }
}

// ---------------- k_graph: chunk-streaming. Each 16-lane group owns RUN
// contiguous nodes; register-accumulates unnormalized e*x and s; flushes to
// global f32 accumulators via atomicAdd at graph boundaries / run end.
__global__ __launch_bounds__(256) void k_graph(
    const float* __restrict__ node_feats, const int* __restrict__ seg,
    const float* __restrict__ W_log, const float* __restrict__ gz,
    float* __restrict__ unorm, float* __restrict__ sden) {
    const int tid = threadIdx.x;
    const int lane = tid & 63;
    const int sl = lane & 15;
    const int gidx = blockIdx.x * 16 + (tid >> 4);
    const int i0 = gidx * RUN;

    const float4 w0 = *(const float4*)(W_log + FEAT + sl * 4);
    const float4 w1 = *(const float4*)(W_log + FEAT + 64 + sl * 4);
    const float4 w2 = *(const float4*)(W_log + FEAT + 128 + sl * 4);
    const float4 w3 = *(const float4*)(W_log + FEAT + 192 + sl * 4);

    float s = 0.f;
    float4 A0 = {0.f, 0.f, 0.f, 0.f}, A1 = A0, A2 = A0, A3 = A0;

#define FLUSH() do { \
    atomicAdd(&unorm[(size_t)cur * FEAT + sl * 4 + 0], A0.x); \
    atomicAdd(&unorm[(size_t)cur * FEAT + sl * 4 + 1], A0.y); \
    atomicAdd(&unorm[(size_t)cur * FEAT + sl * 4 + 2], A0.z); \
    atomicAdd(&unorm[(size_t)cur * FEAT + sl * 4 + 3], A0.w); \
    atomicAdd(&unorm[(size_t)cur * FEAT + 64 + sl * 4 + 0], A1.x); \
    atomicAdd(&unorm[(size_t)cur * FEAT + 64 + sl * 4 + 1], A1.y); \
    atomicAdd(&unorm[(size_t)cur * FEAT + 64 + sl * 4 + 2], A1.z); \
    atomicAdd(&unorm[(size_t)cur * FEAT + 64 + sl * 4 + 3], A1.w); \
    atomicAdd(&unorm[(size_t)cur * FEAT + 128 + sl * 4 + 0], A2.x); \
    atomicAdd(&unorm[(size_t)cur * FEAT + 128 + sl * 4 + 1], A2.y); \
    atomicAdd(&unorm[(size_t)cur * FEAT + 128 + sl * 4 + 2], A2.z); \
    atomicAdd(&unorm[(size_t)cur * FEAT + 128 + sl * 4 + 3], A2.w); \
    atomicAdd(&unorm[(size_t)cur * FEAT + 192 + sl * 4 + 0], A3.x); \
    atomicAdd(&unorm[(size_t)cur * FEAT + 192 + sl * 4 + 1], A3.y); \
    atomicAdd(&unorm[(size_t)cur * FEAT + 192 + sl * 4 + 2], A3.z); \
    atomicAdd(&unorm[(size_t)cur * FEAT + 192 + sl * 4 + 3], A3.w); \
    if (sl == 0) atomicAdd(&sden[cur], s); \
    s = 0.f; \
    A0 = (float4){0.f, 0.f, 0.f, 0.f}; A1 = A0; A2 = A0; A3 = A0; \
} while (0)

    int cur = seg[i0];
    float gzb = gz[cur];
    int sgc = cur;

    const float* row0 = node_feats + (size_t)i0 * FEAT + sl * 4;
    float4 c0 = *(const float4*)(row0);
    float4 c1 = *(const float4*)(row0 + 64);
    float4 c2 = *(const float4*)(row0 + 128);
    float4 c3 = *(const float4*)(row0 + 192);

    for (int j = 0; j < RUN; ++j) {
        // prefetch next node (clamped)
        int jn = (j + 1 < RUN) ? j + 1 : j;
        const float* rn = node_feats + (size_t)(i0 + jn) * FEAT + sl * 4;
        float4 p0 = *(const float4*)(rn);
        float4 p1 = *(const float4*)(rn + 64);
        float4 p2 = *(const float4*)(rn + 128);
        float4 p3 = *(const float4*)(rn + 192);
        int sgn = seg[i0 + jn];

        if (sgc != cur) { FLUSH(); cur = sgc; gzb = gz[cur]; }

        float d0 = c0.x * w0.x + c0.y * w0.y + c0.z * w0.z + c0.w * w0.w;
        float d1 = c1.x * w1.x + c1.y * w1.y + c1.z * w1.z + c1.w * w1.w;
        float d2 = c2.x * w2.x + c2.y * w2.y + c2.z * w2.z + c2.w * w2.w;
        float d3 = c3.x * w3.x + c3.y * w3.y + c3.z * w3.z + c3.w * w3.w;
        float d = (d0 + d1) + (d2 + d3);
        d += __shfl_xor(d, 1);
        d += __shfl_xor(d, 2);
        d += __shfl_xor(d, 4);
        d += __shfl_xor(d, 8);
        float z = gzb + d;
        z = fmaxf(z, 0.f) + 0.01f * fminf(z, 0.f);   // LeakyReLU
        float e = __expf(z);                          // |z| small: no-max softmax
        s += e;
        A0.x = fmaf(e, c0.x, A0.x); A0.y = fmaf(e, c0.y, A0.y);
        A0.z = fmaf(e, c0.z, A0.z); A0.w = fmaf(e, c0.w, A0.w);
        A1.x = fmaf(e, c1.x, A1.x); A1.y = fmaf(e, c1.y, A1.y);
        A1.z = fmaf(e, c1.z, A1.z); A1.w = fmaf(e, c1.w, A1.w);
        A2.x = fmaf(e, c2.x, A2.x); A2.y = fmaf(e, c2.y, A2.y);
        A2.z = fmaf(e, c2.z, A2.z); A2.w = fmaf(e, c2.w, A2.w);
        A3.x = fmaf(e, c3.x, A3.x); A3.y = fmaf(e, c3.y, A3.y);
        A3.z = fmaf(e, c3.z, A3.z); A3.w = fmaf(e, c3.w, A3.w);

        c0 = p0; c1 = p1; c2 = p2; c3 = p3; sgc = sgn;
    }
    FLUSH();
#undef FLUSH
}

// ---------------- fused context + GRU: 32 rows/block, grid 256
__global__ __launch_bounds__(256) void k_ctxgru(
    const float* __restrict__ unorm, const float* __restrict__ sden,
    const unsigned short* __restrict__ wptb, const float* __restrict__ b_proj,
    const float* __restrict__ g_feats, const unsigned short* __restrict__ wihb,
    const unsigned short* __restrict__ whhb, const float* __restrict__ b_ih,
    const float* __restrict__ b_hh, float* __restrict__ out) {
    const int m0 = blockIdx.x * 32;
    const int tid = threadIdx.x;
    const int lane = tid & 63;
    const int wv = tid >> 6;
    const int q = lane >> 4;
    const int fl = lane & 15;

    __shared__ __align__(16) char ldsP[16384];
    __shared__ __align__(16) char ldsC[16384];
    __shared__ __align__(16) char ldsG[16384];

    // stage pooled = unorm/sden (f32 -> bf16) and g_feats (f32 -> bf16), swizzled
#pragma unroll
    for (int p = 0; p < 4; ++p) {
        int c = p * 256 + tid;           // 16B-unit index, 32 units/row
        int row = c >> 5;
        int kb = (c & 31) << 4;
        int dst = row * 512 + (kb ^ ((row & 7) << 4));
        float sd = sden[m0 + row];
        float inv = (sd > 0.f) ? 1.f / sd : 0.f;
        const float* psrc = unorm + (size_t)(m0 + row) * 256 + (c & 31) * 8;
        float4 pa = *(const float4*)psrc;
        float4 pb = *(const float4*)(psrc + 4);
        u16x8 pv;
        pv[0] = f2bf(pa.x * inv); pv[1] = f2bf(pa.y * inv);
        pv[2] = f2bf(pa.z * inv); pv[3] = f2bf(pa.w * inv);
        pv[4] = f2bf(pb.x * inv); pv[5] = f2bf(pb.y * inv);
        pv[6] = f2bf(pb.z * inv); pv[7] = f2bf(pb.w * inv);
        *(u16x8*)(ldsP + dst) = pv;
        const float* gsrc = g_feats + (size_t)(m0 + row) * 256 + (c & 31) * 8;
        float4 ga = *(const float4*)gsrc;
        float4 gb = *(const float4*)(gsrc + 4);
        u16x8 gv;
        gv[0] = f2bf(ga.x); gv[1] = f2bf(ga.y); gv[2] = f2bf(ga.z); gv[3] = f2bf(ga.w);
        gv[4] = f2bf(gb.x); gv[5] = f2bf(gb.y); gv[6] = f2bf(gb.z); gv[7] = f2bf(gb.w);
        *(u16x8*)(ldsG + dst) = gv;
    }
    __syncthreads();

    // ---- phase A: ctx = elu(pooled @ W_proj + flag*b_proj), wave tile 16x128
    {
        const int wm = wv & 1, wn = wv >> 1;
        const int arow = wm * 16 + fl;
        const int aswz = (arow & 7) << 4;
        const char* aP = ldsP + arow * 512;

        f32x4 acc[8];
#pragma unroll
        for (int nf = 0; nf < 8; ++nf) acc[nf] = (f32x4){0.f, 0.f, 0.f, 0.f};

        for (int kk = 0; kk < 8; ++kk) {
            bf16x8 a = *(const bf16x8*)(aP + ((kk * 64 + q * 16) ^ aswz));
#pragma unroll
            for (int nf = 0; nf < 8; ++nf) {
                const char* bp = (const char*)wptb +
                    (size_t)(wn * 128 + nf * 16 + fl) * 512 + q * 16 + kk * 64;
                bf16x8 bv = *(const bf16x8*)bp;
                acc[nf] = __builtin_amdgcn_mfma_f32_16x16x32_bf16(a, bv, acc[nf], 0, 0, 0);
            }
        }
        float flg[4];
#pragma unroll
        for (int j = 0; j < 4; ++j)
            flg[j] = (sden[m0 + wm * 16 + q * 4 + j] > 0.f) ? 1.f : 0.f;
#pragma unroll
        for (int nf = 0; nf < 8; ++nf) {
            int c = wn * 128 + nf * 16 + fl;
            float bp = b_proj[c];
#pragma unroll
            for (int j = 0; j < 4; ++j) {
                int r = wm * 16 + q * 4 + j;
                float v = acc[nf][j] + flg[j] * bp;
                v = (v > 0.f) ? v : expm1f(v);
                *(unsigned short*)(ldsC + r * 512 + ((c * 2) ^ ((r & 7) << 4))) = f2bf(v);
            }
        }
    }
    __syncthreads();

    // ---- phase B: GRU gates, wave tile 16x64, two col passes
    const int wmB = wv & 1;
    const int browL = wmB * 16 + fl;
    const int aswzB = (browL & 7) << 4;
    const char* aC = ldsC + browL * 512;
    const char* aG = ldsG + browL * 512;

    for (int p = 0; p < 2; ++p) {
        const int cb = ((wv >> 1) + p * 2) * 64;
        f32x4 aR[4], aZ[4], aIN[4], aHN[4];
#pragma unroll
        for (int nf = 0; nf < 4; ++nf) {
            aR[nf] = (f32x4){0.f, 0.f, 0.f, 0.f}; aZ[nf] = aR[nf];
            aIN[nf] = aR[nf]; aHN[nf] = aR[nf];
        }
        for (int kk = 0; kk < 8; ++kk) {
            bf16x8 a = *(const bf16x8*)(aC + ((kk * 64 + q * 16) ^ aswzB));
#pragma unroll
            for (int nf = 0; nf < 4; ++nf) {
                const char* base = (const char*)wihb +
                    (size_t)(cb + nf * 16 + fl) * 512 + q * 16 + kk * 64;
                bf16x8 br = *(const bf16x8*)(base);
                bf16x8 bz = *(const bf16x8*)(base + 256 * 512);
                bf16x8 bn = *(const bf16x8*)(base + 512 * 512);
                aR[nf] = __builtin_amdgcn_mfma_f32_16x16x32_bf16(a, br, aR[nf], 0, 0, 0);
                aZ[nf] = __builtin_amdgcn_mfma_f32_16x16x32_bf16(a, bz, aZ[nf], 0, 0, 0);
                aIN[nf] = __builtin_amdgcn_mfma_f32_16x16x32_bf16(a, bn, aIN[nf], 0, 0, 0);
            }
        }
        for (int kk = 0; kk < 8; ++kk) {
            bf16x8 a = *(const bf16x8*)(aG + ((kk * 64 + q * 16) ^ aswzB));
#pragma unroll
            for (int nf = 0; nf < 4; ++nf) {
                const char* base = (const char*)whhb +
                    (size_t)(cb + nf * 16 + fl) * 512 + q * 16 + kk * 64;
                bf16x8 br = *(const bf16x8*)(base);
                bf16x8 bz = *(const bf16x8*)(base + 256 * 512);
                bf16x8 bn = *(const bf16x8*)(base + 512 * 512);
                aR[nf] = __builtin_amdgcn_mfma_f32_16x16x32_bf16(a, br, aR[nf], 0, 0, 0);
                aZ[nf] = __builtin_amdgcn_mfma_f32_16x16x32_bf16(a, bz, aZ[nf], 0, 0, 0);
                aHN[nf] = __builtin_amdgcn_mfma_f32_16x16x32_bf16(a, bn, aHN[nf], 0, 0, 0);
            }
        }
#pragma unroll
        for (int nf = 0; nf < 4; ++nf) {
            int f = cb + nf * 16 + fl;
            float b_r = b_ih[f] + b_hh[f];
            float b_z = b_ih[256 + f] + b_hh[256 + f];
            float b_in = b_ih[512 + f];
            float b_hn = b_hh[512 + f];
#pragma unroll
            for (int j = 0; j < 4; ++j) {
                int r = m0 + wmB * 16 + q * 4 + j;
                float rr = sigmoidf(aR[nf][j] + b_r);
                float zz = sigmoidf(aZ[nf][j] + b_z);
                float nn = tanhf(aIN[nf][j] + b_in + rr * (aHN[nf][j] + b_hn));
                float h = g_feats[(size_t)r * 256 + f];
                out[(size_t)r * 256 + f] = (1.f - zz) * nn + zz * h;
            }
        }
    }
}

extern "C" void kernel_launch(void* const* d_in, const int* in_sizes, int n_in,
                              void* d_out, int out_size, void* d_ws, size_t ws_size,
                              hipStream_t stream) {
    const float* node_feats = (const float*)d_in[0];
    const float* g_feats    = (const float*)d_in[1];
    const int*   seg        = (const int*)d_in[2];
    const float* W_log      = (const float*)d_in[3];
    const float* b_log      = (const float*)d_in[4];
    const float* W_proj     = (const float*)d_in[5];
    const float* b_proj     = (const float*)d_in[6];
    const float* W_ih       = (const float*)d_in[7];
    const float* W_hh       = (const float*)d_in[8];
    const float* b_ih       = (const float*)d_in[9];
    const float* b_hh       = (const float*)d_in[10];
    float* out = (float*)d_out;

    char* ws = (char*)d_ws;
    float* gz    = (float*)ws;                        // 8192 f32
    float* sden  = (float*)(ws + 32768);              // 8192 f32
    float* unorm = (float*)(ws + 65536);              // 8192*256 f32 (8 MB)
    unsigned short* wihb = (unsigned short*)(ws + 65536 + 8388608);
    unsigned short* whhb = (unsigned short*)(ws + 65536 + 8388608 + 393216);
    unsigned short* wptb = (unsigned short*)(ws + 65536 + 8388608 + 2 * 393216);

    hipLaunchKernelGGL(k_prep, dim3(4744), dim3(256), 0, stream,
                       g_feats, W_log, b_log, W_ih, W_hh, W_proj,
                       gz, wihb, whhb, wptb, unorm, sden);
    hipLaunchKernelGGL(k_graph, dim3(NNODES / (RUN * 16)), dim3(256), 0, stream,
                       node_feats, seg, W_log, gz, unorm, sden);
    hipLaunchKernelGGL(k_ctxgru, dim3(NGRAPHS / 32), dim3(256), 0, stream,
                       unorm, sden, wptb, b_proj, g_feats, wihb, whhb, b_ih, b_hh, out);
}

// Round 5
// 120.020 us; speedup vs baseline: 1.6023x; 1.6023x over previous
//
#include <hip/hip_runtime.h>
#include <hip/hip_bf16.h>
#include <math.h>

#define FEAT 256
#define NNODES 262144
#define NGRAPHS 8192

typedef short bf16x8 __attribute__((ext_vector_type(8)));
typedef unsigned short u16x8 __attribute__((ext_vector_type(8)));
typedef float f32x4 __attribute__((ext_vector_type(4)));

__device__ __forceinline__ unsigned short f2bf(float f) {
    unsigned u = __float_as_uint(f);
    u += 0x7fffu + ((u >> 16) & 1u);
    return (unsigned short)(u >> 16);
}

__device__ __forceinline__ float waveReduceSum(float v) {
#pragma unroll
    for (int m = 32; m > 0; m >>= 1) v += __shfl_xor(v, m, 64);
    return v;
}

__device__ __forceinline__ float sigmoidf(float x) { return 1.f / (1.f + expf(-x)); }

// ---------------- fused prep: gz | W_ih->bf16 | W_hh->bf16 | W_proj^T->bf16 | offsets
__global__ __launch_bounds__(256) void k_prep(
    const float* __restrict__ g_feats, const float* __restrict__ W_log,
    const float* __restrict__ b_log, const float* __restrict__ W_ih,
    const float* __restrict__ W_hh, const float* __restrict__ W_proj,
    const int* __restrict__ seg, float* __restrict__ gz,
    unsigned short* __restrict__ wihb, unsigned short* __restrict__ whhb,
    unsigned short* __restrict__ wptb, int* __restrict__ off) {
    const int blk = blockIdx.x;
    const int tid = threadIdx.x;
    if (blk < 2048) {
        // gz[b] = dot(relu(g_feats[b]), W_log[0:F]) + b_log; 4 graphs/block (wave each)
        int gw = blk * 4 + (tid >> 6);
        int lane = tid & 63;
        float4 gf = *(const float4*)(g_feats + (size_t)gw * FEAT + lane * 4);
        float4 wl = *(const float4*)(W_log + lane * 4);
        float d = fmaxf(gf.x, 0.f) * wl.x + fmaxf(gf.y, 0.f) * wl.y +
                  fmaxf(gf.z, 0.f) * wl.z + fmaxf(gf.w, 0.f) * wl.w;
        d = waveReduceSum(d);
        if (lane == 0) gz[gw] = d + b_log[0];
    } else if (blk < 2240) {  // W_ih -> bf16, 192 blocks x 1024 elems
        int i = (blk - 2048) * 1024 + tid * 4;
        float4 v = *(const float4*)(W_ih + i);
        ushort4 o;
        o.x = f2bf(v.x); o.y = f2bf(v.y); o.z = f2bf(v.z); o.w = f2bf(v.w);
        *(ushort4*)(wihb + i) = o;
    } else if (blk < 2432) {  // W_hh -> bf16
        int i = (blk - 2240) * 1024 + tid * 4;
        float4 v = *(const float4*)(W_hh + i);
        ushort4 o;
        o.x = f2bf(v.x); o.y = f2bf(v.y); o.z = f2bf(v.z); o.w = f2bf(v.w);
        *(ushort4*)(whhb + i) = o;
    } else if (blk < 2688) {  // Wt[f][k] = W_proj[k][f], 256 blocks
        int f = blk - 2432;
        wptb[f * 256 + tid] = f2bf(W_proj[tid * 256 + f]);
    } else {  // offsets, 33 blocks
        int b = (blk - 2688) * 256 + tid;
        if (b > NGRAPHS) return;
        int lo = 0, hi = NNODES;
        while (lo < hi) {
            int mid = (lo + hi) >> 1;
            if (seg[mid] < b) lo = mid + 1; else hi = mid;
        }
        off[b] = lo;
    }
}

// ---------------- k_graph: one block/graph, single pass, NO-max softmax,
// 16-lane groups (4 nodes in flight per wave) + register prefetch of next node.
__global__ __launch_bounds__(256, 4) void k_graph(
    const float* __restrict__ node_feats, const int* __restrict__ off,
    const float* __restrict__ W_log, const float* __restrict__ gz,
    unsigned short* __restrict__ pooled, float* __restrict__ asum_out) {
    const int b = blockIdx.x;
    const int tid = threadIdx.x;
    const int lane = tid & 63;
    const int wv = tid >> 6;
    const int grp = lane >> 4;
    const int sl = lane & 15;

    const int start = off[b];
    const int end = off[b + 1];

    __shared__ float wAcc[4][FEAT];
    __shared__ float wS[4];

    if (end - start == 0) {
        pooled[(size_t)b * FEAT + tid] = 0;
        if (tid == 0) asum_out[b] = 0.f;
        return;
    }

    // this lane's 16 feature slots: f = q*64 + sl*4 + j
    const float4 w0 = *(const float4*)(W_log + FEAT + sl * 4);
    const float4 w1 = *(const float4*)(W_log + FEAT + 64 + sl * 4);
    const float4 w2 = *(const float4*)(W_log + FEAT + 128 + sl * 4);
    const float4 w3 = *(const float4*)(W_log + FEAT + 192 + sl * 4);
    const float gzb = gz[b];

    float s = 0.f;
    float4 A0 = {0.f, 0.f, 0.f, 0.f}, A1 = A0, A2 = A0, A3 = A0;

    int i = start + wv * 4 + grp;
    if (i < end) {
        const float* r = node_feats + (size_t)i * FEAT + sl * 4;
        float4 c0 = *(const float4*)(r);
        float4 c1 = *(const float4*)(r + 64);
        float4 c2 = *(const float4*)(r + 128);
        float4 c3 = *(const float4*)(r + 192);
        while (true) {
            // prefetch next node (clamped tail prefetch hits L1, no HBM cost)
            int inx = i + 16;
            int ip = (inx < end) ? inx : i;
            const float* rp = node_feats + (size_t)ip * FEAT + sl * 4;
            float4 p0 = *(const float4*)(rp);
            float4 p1 = *(const float4*)(rp + 64);
            float4 p2 = *(const float4*)(rp + 128);
            float4 p3 = *(const float4*)(rp + 192);

            float d0 = c0.x * w0.x + c0.y * w0.y + c0.z * w0.z + c0.w * w0.w;
            float d1 = c1.x * w1.x + c1.y * w1.y + c1.z * w1.z + c1.w * w1.w;
            float d2 = c2.x * w2.x + c2.y * w2.y + c2.z * w2.z + c2.w * w2.w;
            float d3 = c3.x * w3.x + c3.y * w3.y + c3.z * w3.z + c3.w * w3.w;
            float d = (d0 + d1) + (d2 + d3);
            d += __shfl_xor(d, 1);
            d += __shfl_xor(d, 2);
            d += __shfl_xor(d, 4);
            d += __shfl_xor(d, 8);
            float z = gzb + d;
            z = fmaxf(z, 0.f) + 0.01f * fminf(z, 0.f);  // LeakyReLU
            float e = __expf(z);  // |z| <= ~3.3 by construction: no max needed
            s += e;
            A0.x = fmaf(e, c0.x, A0.x); A0.y = fmaf(e, c0.y, A0.y);
            A0.z = fmaf(e, c0.z, A0.z); A0.w = fmaf(e, c0.w, A0.w);
            A1.x = fmaf(e, c1.x, A1.x); A1.y = fmaf(e, c1.y, A1.y);
            A1.z = fmaf(e, c1.z, A1.z); A1.w = fmaf(e, c1.w, A1.w);
            A2.x = fmaf(e, c2.x, A2.x); A2.y = fmaf(e, c2.y, A2.y);
            A2.z = fmaf(e, c2.z, A2.z); A2.w = fmaf(e, c2.w, A2.w);
            A3.x = fmaf(e, c3.x, A3.x); A3.y = fmaf(e, c3.y, A3.y);
            A3.z = fmaf(e, c3.z, A3.z); A3.w = fmaf(e, c3.w, A3.w);

            c0 = p0; c1 = p1; c2 = p2; c3 = p3;
            i = inx;
            if (i >= end) break;
        }
    }

    // merge the 4 groups: xor-16 then xor-32 sums
#define MRG(X) X += __shfl_xor(X, 16); X += __shfl_xor(X, 32);
    MRG(A0.x) MRG(A0.y) MRG(A0.z) MRG(A0.w)
    MRG(A1.x) MRG(A1.y) MRG(A1.z) MRG(A1.w)
    MRG(A2.x) MRG(A2.y) MRG(A2.z) MRG(A2.w)
    MRG(A3.x) MRG(A3.y) MRG(A3.z) MRG(A3.w)
    MRG(s)
#undef MRG

    if (grp == 0) {
        *(float4*)&wAcc[wv][sl * 4] = A0;
        *(float4*)&wAcc[wv][64 + sl * 4] = A1;
        *(float4*)&wAcc[wv][128 + sl * 4] = A2;
        *(float4*)&wAcc[wv][192 + sl * 4] = A3;
        if (sl == 0) wS[wv] = s;
    }
    __syncthreads();

    float val = (wAcc[0][tid] + wAcc[1][tid]) + (wAcc[2][tid] + wAcc[3][tid]);
    float S = (wS[0] + wS[1]) + (wS[2] + wS[3]);
    pooled[(size_t)b * FEAT + tid] = f2bf(val / S);
    if (tid == 0) asum_out[b] = 1.f;
}

// ---------------- fused context + GRU: 32 rows/block, grid 256
// LDS: pooled(bf16,swz) -> phaseA GEMM -> ctx(bf16,swz in LDS) -> phaseB gates
__global__ __launch_bounds__(256) void k_ctxgru(
    const unsigned short* __restrict__ pooled, const float* __restrict__ asum,
    const unsigned short* __restrict__ wptb, const float* __restrict__ b_proj,
    const float* __restrict__ g_feats, const unsigned short* __restrict__ wihb,
    const unsigned short* __restrict__ whhb, const float* __restrict__ b_ih,
    const float* __restrict__ b_hh, float* __restrict__ out) {
    const int m0 = blockIdx.x * 32;
    const int tid = threadIdx.x;
    const int lane = tid & 63;
    const int wv = tid >> 6;
    const int q = lane >> 4;
    const int fl = lane & 15;

    __shared__ __align__(16) char ldsP[16384];
    __shared__ __align__(16) char ldsC[16384];
    __shared__ __align__(16) char ldsG[16384];

    // stage pooled (bf16 copy) and g_feats (f32 -> bf16), both swizzled
#pragma unroll
    for (int p = 0; p < 4; ++p) {
        int c = p * 256 + tid;           // 16B-unit index, 32 units/row
        int row = c >> 5;
        int kb = (c & 31) << 4;
        int dst = row * 512 + (kb ^ ((row & 7) << 4));
        *(uint4*)(ldsP + dst) = *(const uint4*)((const char*)pooled + (size_t)m0 * 512 + c * 16);
        const float* gsrc = g_feats + (size_t)(m0 + row) * 256 + (c & 31) * 8;
        float4 ga = *(const float4*)gsrc;
        float4 gb = *(const float4*)(gsrc + 4);
        u16x8 gv;
        gv[0] = f2bf(ga.x); gv[1] = f2bf(ga.y); gv[2] = f2bf(ga.z); gv[3] = f2bf(ga.w);
        gv[4] = f2bf(gb.x); gv[5] = f2bf(gb.y); gv[6] = f2bf(gb.z); gv[7] = f2bf(gb.w);
        *(u16x8*)(ldsG + dst) = gv;
    }
    __syncthreads();

    // ---- phase A: ctx = elu(pooled @ W_proj + asum*b_proj), wave tile 16x128
    {
        const int wm = wv & 1, wn = wv >> 1;
        const int arow = wm * 16 + fl;
        const int aswz = (arow & 7) << 4;
        const char* aP = ldsP + arow * 512;

        f32x4 acc[8];
#pragma unroll
        for (int nf = 0; nf < 8; ++nf) acc[nf] = (f32x4){0.f, 0.f, 0.f, 0.f};

        for (int kk = 0; kk < 8; ++kk) {
            bf16x8 a = *(const bf16x8*)(aP + ((kk * 64 + q * 16) ^ aswz));
#pragma unroll
            for (int nf = 0; nf < 8; ++nf) {
                const char* bp = (const char*)wptb +
                    (size_t)(wn * 128 + nf * 16 + fl) * 512 + q * 16 + kk * 64;
                bf16x8 bv = *(const bf16x8*)bp;
                acc[nf] = __builtin_amdgcn_mfma_f32_16x16x32_bf16(a, bv, acc[nf], 0, 0, 0);
            }
        }
        float as_[4];
#pragma unroll
        for (int j = 0; j < 4; ++j) as_[j] = asum[m0 + wm * 16 + q * 4 + j];
#pragma unroll
        for (int nf = 0; nf < 8; ++nf) {
            int c = wn * 128 + nf * 16 + fl;
            float bp = b_proj[c];
#pragma unroll
            for (int j = 0; j < 4; ++j) {
                int r = wm * 16 + q * 4 + j;
                float v = acc[nf][j] + as_[j] * bp;
                v = (v > 0.f) ? v : expm1f(v);
                *(unsigned short*)(ldsC + r * 512 + ((c * 2) ^ ((r & 7) << 4))) = f2bf(v);
            }
        }
    }
    __syncthreads();

    // ---- phase B: GRU gates, wave tile 16x64, two col passes
    const int wmB = wv & 1;
    const int browL = wmB * 16 + fl;
    const int aswzB = (browL & 7) << 4;
    const char* aC = ldsC + browL * 512;
    const char* aG = ldsG + browL * 512;

    for (int p = 0; p < 2; ++p) {
        const int cb = ((wv >> 1) + p * 2) * 64;
        f32x4 aR[4], aZ[4], aIN[4], aHN[4];
#pragma unroll
        for (int nf = 0; nf < 4; ++nf) {
            aR[nf] = (f32x4){0.f, 0.f, 0.f, 0.f}; aZ[nf] = aR[nf];
            aIN[nf] = aR[nf]; aHN[nf] = aR[nf];
        }
        for (int kk = 0; kk < 8; ++kk) {
            bf16x8 a = *(const bf16x8*)(aC + ((kk * 64 + q * 16) ^ aswzB));
#pragma unroll
            for (int nf = 0; nf < 4; ++nf) {
                const char* base = (const char*)wihb +
                    (size_t)(cb + nf * 16 + fl) * 512 + q * 16 + kk * 64;
                bf16x8 br = *(const bf16x8*)(base);
                bf16x8 bz = *(const bf16x8*)(base + 256 * 512);
                bf16x8 bn = *(const bf16x8*)(base + 512 * 512);
                aR[nf] = __builtin_amdgcn_mfma_f32_16x16x32_bf16(a, br, aR[nf], 0, 0, 0);
                aZ[nf] = __builtin_amdgcn_mfma_f32_16x16x32_bf16(a, bz, aZ[nf], 0, 0, 0);
                aIN[nf] = __builtin_amdgcn_mfma_f32_16x16x32_bf16(a, bn, aIN[nf], 0, 0, 0);
            }
        }
        for (int kk = 0; kk < 8; ++kk) {
            bf16x8 a = *(const bf16x8*)(aG + ((kk * 64 + q * 16) ^ aswzB));
#pragma unroll
            for (int nf = 0; nf < 4; ++nf) {
                const char* base = (const char*)whhb +
                    (size_t)(cb + nf * 16 + fl) * 512 + q * 16 + kk * 64;
                bf16x8 br = *(const bf16x8*)(base);
                bf16x8 bz = *(const bf16x8*)(base + 256 * 512);
                bf16x8 bn = *(const bf16x8*)(base + 512 * 512);
                aR[nf] = __builtin_amdgcn_mfma_f32_16x16x32_bf16(a, br, aR[nf], 0, 0, 0);
                aZ[nf] = __builtin_amdgcn_mfma_f32_16x16x32_bf16(a, bz, aZ[nf], 0, 0, 0);
                aHN[nf] = __builtin_amdgcn_mfma_f32_16x16x32_bf16(a, bn, aHN[nf], 0, 0, 0);
            }
        }
#pragma unroll
        for (int nf = 0; nf < 4; ++nf) {
            int f = cb + nf * 16 + fl;
            float b_r = b_ih[f] + b_hh[f];
            float b_z = b_ih[256 + f] + b_hh[256 + f];
            float b_in = b_ih[512 + f];
            float b_hn = b_hh[512 + f];
#pragma unroll
            for (int j = 0; j < 4; ++j) {
                int r = m0 + wmB * 16 + q * 4 + j;
                float rr = sigmoidf(aR[nf][j] + b_r);
                float zz = sigmoidf(aZ[nf][j] + b_z);
                float nn = tanhf(aIN[nf][j] + b_in + rr * (aHN[nf][j] + b_hn));
                float h = g_feats[(size_t)r * 256 + f];
                out[(size_t)r * 256 + f] = (1.f - zz) * nn + zz * h;
            }
        }
    }
}

extern "C" void kernel_launch(void* const* d_in, const int* in_sizes, int n_in,
                              void* d_out, int out_size, void* d_ws, size_t ws_size,
                              hipStream_t stream) {
    const float* node_feats = (const float*)d_in[0];
    const float* g_feats    = (const float*)d_in[1];
    const int*   seg        = (const int*)d_in[2];
    const float* W_log      = (const float*)d_in[3];
    const float* b_log      = (const float*)d_in[4];
    const float* W_proj     = (const float*)d_in[5];
    const float* b_proj     = (const float*)d_in[6];
    const float* W_ih       = (const float*)d_in[7];
    const float* W_hh       = (const float*)d_in[8];
    const float* b_ih       = (const float*)d_in[9];
    const float* b_hh       = (const float*)d_in[10];
    float* out = (float*)d_out;

    char* ws = (char*)d_ws;
    int*   off   = (int*)ws;                                   // [8448] ints
    float* gz    = (float*)(ws + 33792);                       // [8192]
    float* asumw = (float*)(ws + 66560);                       // [8192]
    unsigned short* pooled = (unsigned short*)(ws + 99328);    // 8192*256 bf16
    unsigned short* wihb   = (unsigned short*)(ws + 99328 + 4194304);
    unsigned short* whhb   = (unsigned short*)(ws + 99328 + 4194304 + 393216);
    unsigned short* wptb   = (unsigned short*)(ws + 99328 + 4194304 + 2 * 393216);

    hipLaunchKernelGGL(k_prep, dim3(2721), dim3(256), 0, stream,
                       g_feats, W_log, b_log, W_ih, W_hh, W_proj, seg,
                       gz, wihb, whhb, wptb, off);
    hipLaunchKernelGGL(k_graph, dim3(NGRAPHS), dim3(256), 0, stream,
                       node_feats, off, W_log, gz, pooled, asumw);
    hipLaunchKernelGGL(k_ctxgru, dim3(NGRAPHS / 32), dim3(256), 0, stream,
                       pooled, asumw, wptb, b_proj, g_feats, wihb, whhb, b_ih, b_hh, out);
}